// Round 6
// baseline (253.009 us; speedup 1.0000x reference)
//
#include <hip/hip_runtime.h>
#include <hip/hip_bf16.h>

#define TPB 256
#define PREP_BLOCKS 64

typedef __attribute__((ext_vector_type(8))) short short8;
typedef __attribute__((ext_vector_type(4))) float f32x4;

// ---- weight image byte offsets in d_ws (read directly from global/L2) ----
// All MFMA weight fragments use the K-permutation
//   phys_k(s, q, j) = 16*(2*s + (j>>2)) + 4*q + (j&3)
// which makes every layer's B-fragment register-local in the lane that owns
// batch row b (lane&15), since C-layout rows are 16*mt + 4*quad + r.
#define G_W2F   0        // [t=3][s=4][lane=64][j=8] bf16  12288  (A-frags, perm)
#define G_MVF   12288    // [s=4][64][8] bf16               4096  (A-frags, perm)
#define G_D1F   16384    // [t=2][64][8] bf16               2048  (A-frags, perm)
#define G_D2F   18432    // [64][8] bf16                    1024  (A-frags, perm)
#define G_CEAB  19456    // [e=4][n=128][4] bf16 {a0,a1,a2,ce} 4096
#define G_B2P   23552    // [48] f32 (pad 0)
#define G_B3    23744    // [128] f32
#define G_BMV   24256    // [16] f32 (bm|bv)
#define G_D1C   24320    // [32] f32 (Wd1 col0 + bd1)
#define G_BD2   24448    // [16] f32 (pad 0)
#define G_W3F   24512    // [nt=8][s=2][64][8] bf16        16384  (A-frags, perm)
#define G_END   40896

__device__ __forceinline__ unsigned short f2bf(float f) {
    unsigned int u = __float_as_uint(f);
    unsigned int r = u + 0x7fffu + ((u >> 16) & 1u);   // RNE
    return (unsigned short)(r >> 16);
}
__device__ __forceinline__ unsigned int pk(float a, float b) {
    __hip_bfloat162 h = __float22bfloat162_rn(make_float2(a, b));
    unsigned int u; __builtin_memcpy(&u, &h, 4); return u;
}

__global__ void prep_kernel(
    const float* __restrict__ W1, const float* __restrict__ b1,
    const float* __restrict__ W2, const float* __restrict__ b2,
    const float* __restrict__ W3, const float* __restrict__ b3,
    const float* __restrict__ Wm, const float* __restrict__ bm,
    const float* __restrict__ Wv, const float* __restrict__ bv,
    const float* __restrict__ Wd1, const float* __restrict__ bd1,
    const float* __restrict__ Wd2, const float* __restrict__ bd2,
    unsigned char* __restrict__ ws)
{
    const int g0 = blockIdx.x * TPB + threadIdx.x;
    const int gs = gridDim.x * TPB;
    // W2 as A-fragments of s^T = W2 . x1^T, permuted K
    unsigned short* w2f = (unsigned short*)(ws + G_W2F);
    for (int i = g0; i < 6144; i += gs) {
        int j = i & 7, lane = (i >> 3) & 63, ts = i >> 9;
        int t = ts >> 2, s = ts & 3, q = lane >> 4;
        int n = 16 * t + (lane & 15);
        int phys = 16 * (2 * s + (j >> 2)) + 4 * q + (j & 3);   // 0..127
        w2f[i] = (n < 39) ? f2bf(W2[n * 128 + phys]) : 0;
    }
    // W3 as A-fragments of x3^T = W3 . s^T, permuted K (39 padded to 64)
    unsigned short* w3f = (unsigned short*)(ws + G_W3F);
    for (int i = g0; i < 8192; i += gs) {
        int j = i & 7, lane = (i >> 3) & 63, ns = i >> 9;
        int nt = ns >> 1, s = ns & 1, q = lane >> 4;
        int n = 16 * nt + (lane & 15);
        int phys = 16 * (2 * s + (j >> 2)) + 4 * q + (j & 3);   // 0..63
        w3f[i] = (phys < 39) ? f2bf(W3[n * 39 + phys]) : 0;
    }
    // Wm|Wv as A-fragments, permuted K=128
    unsigned short* mvf = (unsigned short*)(ws + G_MVF);
    for (int i = g0; i < 2048; i += gs) {
        int j = i & 7, lane = (i >> 3) & 63, s = i >> 9;
        int q = lane >> 4, n = lane & 15;
        int phys = 16 * (2 * s + (j >> 2)) + 4 * q + (j & 3);
        mvf[i] = f2bf(n < 8 ? Wm[n * 128 + phys] : Wv[(n - 8) * 128 + phys]);
    }
    // Wd1 (cols 5..24) as A-fragments, permuted K=32 (20 padded)
    unsigned short* d1f = (unsigned short*)(ws + G_D1F);
    for (int i = g0; i < 1024; i += gs) {
        int j = i & 7, lane = (i >> 3) & 63, tt = i >> 9;
        int q = lane >> 4, n = 16 * tt + (lane & 15);
        int phys = 16 * (j >> 2) + 4 * q + (j & 3);             // 0..31
        d1f[i] = (phys < 20) ? f2bf(Wd1[n * 25 + 5 + phys]) : 0;
    }
    // Wd2 as A-fragments, permuted K=32
    unsigned short* d2f = (unsigned short*)(ws + G_D2F);
    for (int i = g0; i < 512; i += gs) {
        int j = i & 7, lane = i >> 3;
        int q = lane >> 4, n = lane & 15;
        int phys = 16 * (j >> 2) + 4 * q + (j & 3);
        d2f[i] = (n < 12) ? f2bf(Wd2[n * 32 + phys]) : 0;
    }
    unsigned short* ceab = (unsigned short*)(ws + G_CEAB);
    for (int i = g0; i < 2048; i += gs) {           // [e][n][4] {a0,a1,a2,ce}
        int c = i & 3, n = (i >> 2) & 127, e = i >> 9;
        float v = (c < 3) ? W1[n * 13 + 10 + c]
                          : (W1[n * 13 + 0] + W1[n * 13 + 6 + e] + b1[n]);
        ceab[i] = f2bf(v);
    }
    float* fb = (float*)(ws + G_B2P);
    for (int i = g0; i < 48; i += gs) fb[i] = (i < 39) ? b2[i] : 0.f;
    fb = (float*)(ws + G_B3);
    for (int i = g0; i < 128; i += gs) fb[i] = b3[i];
    fb = (float*)(ws + G_BMV);
    for (int i = g0; i < 16; i += gs) fb[i] = (i < 8) ? bm[i] : bv[i - 8];
    fb = (float*)(ws + G_D1C);
    for (int i = g0; i < 32; i += gs) fb[i] = Wd1[i * 25 + 0] + bd1[i];
    fb = (float*)(ws + G_BD2);
    for (int i = g0; i < 16; i += gs) fb[i] = (i < 12) ? bd2[i] : 0.f;
}

union S8 { short8 v; uint4 u; };

#define MFMA(a, b, c) __builtin_amdgcn_mfma_f32_16x16x32_bf16(a, b, c, 0, 0, 0)

// Zero LDS, 1 batch tile per wave, ALL weight fragments streamed from L2
// (nothing resident), biases loaded per use. __launch_bounds__(TPB,4) forces
// VGPR <= 64 -> 8 waves/SIMD capacity (the occupancy step r0..r5 never hit).
// Spill signature if the body doesn't fit: WRITE_SIZE >> 37 MB.
__global__ __launch_bounds__(TPB, 4) void vae_mfma(
    const float* __restrict__ ic, const float* __restrict__ cc,
    const float* __restrict__ eps,
    const unsigned char* __restrict__ ws,
    float* __restrict__ out, int B)
{
    const int tid = threadIdx.x;
    const int lane = tid & 63, w = tid >> 6;
    const int quad = lane >> 4, n16 = lane & 15;
    const bool q0 = (quad == 0);
    const long rb = ((long)blockIdx.x * 4 + w) * 16;
    const long Rl = rb + n16;              // this lane's batch row

    // ---- q0 lanes: predicate packs per edge (pre-packed bf16 pairs, 8 u32) ----
    unsigned int bpx[4] = {0,0,0,0}, bpy[4] = {0,0,0,0};
    if (q0) {
        const float* crow = cc + Rl * 30;
        float2 u0 = *(const float2*)(crow);
        float2 u1 = *(const float2*)(crow + 2);
        float2 u2 = *(const float2*)(crow + 10);
        float2 u3 = *(const float2*)(crow + 12);
        bpx[0] = pk(u0.x, u2.x); bpy[0] = pk(crow[14], 1.0f);
        bpx[1] = pk(u0.y, u2.y); bpy[1] = pk(crow[18], 1.0f);
        bpx[2] = pk(u1.x, u3.x); bpy[2] = pk(crow[22], 1.0f);
        bpx[3] = pk(u1.y, u3.y); bpy[3] = pk(crow[26], 1.0f);
    }

    const float* b2p = (const float*)(ws + G_B2P);
    f32x4 ss0 = {0,0,0,0}, ss1 = {0,0,0,0}, ss2 = {0,0,0,0};

    // ---- message MLP: L1 (x1^T tiles) -> in-reg pack -> L2 (s^T), per edge ----
    #pragma unroll
    for (int e = 0; e < 4; e++) {
        S8 bp;                                   // B = p-vector (k=0..3 in q0)
        bp.u.x = bpx[e]; bp.u.y = bpy[e]; bp.u.z = 0u; bp.u.w = 0u;
        const unsigned long long* cb =
            (const unsigned long long*)(ws + G_CEAB + e * 1024);
        S8 xf[4];                                // x1^T B-frags for L2 (perm K)
        #pragma unroll
        for (int mt = 0; mt < 8; mt++) {
            unsigned long long bw = cb[mt * 16 + n16];
            S8 af;                               // A = ceab rows (k=0..3 in q0)
            af.u.x = q0 ? (unsigned int)bw : 0u;
            af.u.y = q0 ? (unsigned int)(bw >> 32) : 0u;
            af.u.z = 0u; af.u.w = 0u;
            f32x4 z4 = {0,0,0,0};
            f32x4 cr = MFMA(af.v, bp.v, z4);     // lane: x1[b=n16][16mt+4q+r]
            unsigned int lo = pk(fmaxf(cr[0], 0.f), fmaxf(cr[1], 0.f));
            unsigned int hi = pk(fmaxf(cr[2], 0.f), fmaxf(cr[3], 0.f));
            if ((mt & 1) == 0) { xf[mt >> 1].u.x = lo; xf[mt >> 1].u.y = hi; }
            else               { xf[mt >> 1].u.z = lo; xf[mt >> 1].u.w = hi; }
        }
        // biases loaded per edge (not held across the kernel)
        f32x4 c0 = *(const f32x4*)(b2p + 4 * quad);
        f32x4 c1 = *(const f32x4*)(b2p + 16 + 4 * quad);
        f32x4 c2 = *(const f32x4*)(b2p + 32 + 4 * quad);
        #pragma unroll
        for (int s = 0; s < 4; s++) {            // W2 frags streamed from L2
            S8 w0, w1, w2;
            w0.u = *(const uint4*)(ws + G_W2F + ((s) * 64 + lane) * 16);
            w1.u = *(const uint4*)(ws + G_W2F + ((4 + s) * 64 + lane) * 16);
            w2.u = *(const uint4*)(ws + G_W2F + ((8 + s) * 64 + lane) * 16);
            c0 = MFMA(w0.v, xf[s].v, c0);
            c1 = MFMA(w1.v, xf[s].v, c1);
            c2 = MFMA(w2.v, xf[s].v, c2);
        }
        #pragma unroll
        for (int r = 0; r < 4; r++) {
            ss0[r] += fmaxf(c0[r], 0.f);
            ss1[r] += fmaxf(c1[r], 0.f);
            ss2[r] += fmaxf(c2[r], 0.f);
        }
    }

    // ---- s^T B-frags (K=64, tiles 3 valid + 1 zero pad) ----
    S8 sf0, sf1;
    sf0.u.x = pk(ss0[0], ss0[1]); sf0.u.y = pk(ss0[2], ss0[3]);
    sf0.u.z = pk(ss1[0], ss1[1]); sf0.u.w = pk(ss1[2], ss1[3]);
    sf1.u.x = pk(ss2[0], ss2[1]); sf1.u.y = pk(ss2[2], ss2[3]);
    sf1.u.z = 0u; sf1.u.w = 0u;   // rows 48..63 pad (rows 39..47 exact zero)

    // ---- L3: x3^T = W3 . s^T ; pack heads B-frags on the fly ----
    const uint4* w3g = (const uint4*)(ws + G_W3F);
    const float* b3p = (const float*)(ws + G_B3);
    S8 hf[4];
    #pragma unroll
    for (int nt = 0; nt < 8; nt++) {
        f32x4 c = *(const f32x4*)(b3p + nt * 16 + 4 * quad);
        S8 a0, a1;
        a0.u = w3g[(nt * 2 + 0) * 64 + lane];
        a1.u = w3g[(nt * 2 + 1) * 64 + lane];
        c = MFMA(a0.v, sf0.v, c);
        c = MFMA(a1.v, sf1.v, c);
        unsigned int lo = pk(fmaxf(c[0], 0.f), fmaxf(c[1], 0.f));
        unsigned int hi = pk(fmaxf(c[2], 0.f), fmaxf(c[3], 0.f));
        if ((nt & 1) == 0) { hf[nt >> 1].u.x = lo; hf[nt >> 1].u.y = hi; }
        else               { hf[nt >> 1].u.z = lo; hf[nt >> 1].u.w = hi; }
    }

    // ---- heads: [mn|lv]^T, lane holds rows 4q+r of (mn0..7,lv0..7) ----
    f32x4 cm = *(const f32x4*)((const float*)(ws + G_BMV) + 4 * quad);
    #pragma unroll
    for (int s = 0; s < 4; s++) {
        S8 a; a.u = *(const uint4*)(ws + G_MVF + (s * 64 + lane) * 16);
        cm = MFMA(a.v, hf[s].v, cm);
    }

    // ---- reparameterization: lv lives in q2/q3, pull to q0/q1 ----
    const int addrLv = ((lane + 32) & 63) << 2;
    float lvv[4];
    #pragma unroll
    for (int r = 0; r < 4; r++)
        lvv[r] = __int_as_float(
            __builtin_amdgcn_ds_bpermute(addrLv, __float_as_int(cm[r])));
    float4 ev = *(const float4*)(eps + Rl * 8 + 4 * (quad & 1));
    f32x4 zz;
    zz[0] = fmaf(ev.x, __expf(0.5f * lvv[0]), cm[0]);
    zz[1] = fmaf(ev.y, __expf(0.5f * lvv[1]), cm[1]);
    zz[2] = fmaf(ev.z, __expf(0.5f * lvv[2]), cm[2]);
    zz[3] = fmaf(ev.w, __expf(0.5f * lvv[3]), cm[3]);
    // stores: q0/q1 -> means, q2/q3 -> logvar; q0/q1 -> z
    float* pml = (float*)((quad < 2) ? (out + (long)B * 12) : (out + (long)B * 20));
    *(float4*)(pml + Rl * 8 + 4 * (quad & 1)) = *(float4*)&cm;
    if (quad < 2)
        *(float4*)(out + (long)B * 28 + Rl * 8 + 4 * quad) = *(float4*)&zz;

    // ---- z exchange for decoder: q0 needs z[4..7] (from q1), q3 needs z[0..3] (from q0)
    const int addrZ = (n16 + (q0 ? 16 : 0)) << 2;
    float zr[4];
    #pragma unroll
    for (int r = 0; r < 4; r++)
        zr[r] = __int_as_float(
            __builtin_amdgcn_ds_bpermute(addrZ, __float_as_int(zz[r])));

    // ---- decoder input B-frag: phys = [icO(12) | z(8) | 0-pad] permuted ----
    const float* irow = ic + Rl * 30;
    float d0, d1, d2, d3;
    if (quad == 3)      { d0 = zr[0];    d1 = zr[1];    d2 = zr[2];    d3 = zr[3]; }
    else if (quad == 2) { d0 = irow[14]; d1 = irow[18]; d2 = irow[22]; d3 = irow[26]; }
    else {
        const float* p = irow + (quad ? 10 : 0);
        float2 u0 = *(const float2*)(p);
        float2 u1 = *(const float2*)(p + 2);
        d0 = u0.x; d1 = u0.y; d2 = u1.x; d3 = u1.y;
    }
    S8 df;
    df.u.x = pk(d0, d1);
    df.u.y = pk(d2, d3);
    df.u.z = q0 ? pk(zr[0], zr[1]) : 0u;
    df.u.w = q0 ? pk(zr[2], zr[3]) : 0u;

    // ---- decoder layer 1: h^T (2 tiles) ----
    const float* d1c = (const float*)(ws + G_D1C);
    S8 a;
    f32x4 ct = *(const f32x4*)(d1c + 4 * quad);
    a.u = *(const uint4*)(ws + G_D1F + (0 * 64 + lane) * 16);
    f32x4 h0 = MFMA(a.v, df.v, ct);
    ct = *(const f32x4*)(d1c + 16 + 4 * quad);
    a.u = *(const uint4*)(ws + G_D1F + (1 * 64 + lane) * 16);
    f32x4 h1 = MFMA(a.v, df.v, ct);
    S8 hf2;
    hf2.u.x = pk(fmaxf(h0[0], 0.f), fmaxf(h0[1], 0.f));
    hf2.u.y = pk(fmaxf(h0[2], 0.f), fmaxf(h0[3], 0.f));
    hf2.u.z = pk(fmaxf(h1[0], 0.f), fmaxf(h1[1], 0.f));
    hf2.u.w = pk(fmaxf(h1[2], 0.f), fmaxf(h1[3], 0.f));

    // ---- decoder layer 2 + sigmoid + coalesced float4 recon store ----
    f32x4 c2 = *(const f32x4*)((const float*)(ws + G_BD2) + 4 * quad);
    S8 a2; a2.u = *(const uint4*)(ws + G_D2F + lane * 16);
    c2 = MFMA(a2.v, hf2.v, c2);
    if (quad < 3) {
        float4 o;
        o.x = 1.f / (1.f + __expf(-c2[0]));
        o.y = 1.f / (1.f + __expf(-c2[1]));
        o.z = 1.f / (1.f + __expf(-c2[2]));
        o.w = 1.f / (1.f + __expf(-c2[3]));
        *(float4*)(out + Rl * 12 + 4 * quad) = o;
    }
}

extern "C" void kernel_launch(void* const* d_in, const int* in_sizes, int n_in,
                              void* d_out, int out_size, void* d_ws, size_t ws_size,
                              hipStream_t stream) {
    const float* ic  = (const float*)d_in[0];   // initial_c [B,30]
    const float* cc  = (const float*)d_in[2];   // current_c [B,30]
    const float* eps = (const float*)d_in[3];   // eps [B,8]

    const int B = in_sizes[3] / 8;              // 262144
    const int nblocks = B / 64;                 // 4096

    prep_kernel<<<PREP_BLOCKS, TPB, 0, stream>>>(
        (const float*)d_in[4],  (const float*)d_in[5],
        (const float*)d_in[6],  (const float*)d_in[7],
        (const float*)d_in[8],  (const float*)d_in[9],
        (const float*)d_in[10], (const float*)d_in[11],
        (const float*)d_in[12], (const float*)d_in[13],
        (const float*)d_in[14], (const float*)d_in[15],
        (const float*)d_in[16], (const float*)d_in[17],
        (unsigned char*)d_ws);
    vae_mfma<<<nblocks, TPB, 0, stream>>>(
        ic, cc, eps, (const unsigned char*)d_ws, (float*)d_out, B);
}

// Round 7
// 181.761 us; speedup vs baseline: 1.3920x; 1.3920x over previous
//
#include <hip/hip_runtime.h>
#include <hip/hip_bf16.h>

#define TPB 256
#define PREP_BLOCKS 64

typedef __attribute__((ext_vector_type(8))) short short8;
typedef __attribute__((ext_vector_type(4))) float f32x4;

// ---- weight image byte offsets (d_ws; whole image mirrored in LDS) ----
// All MFMA weight fragments use the K-permutation
//   phys_k(s, q, j) = 16*(2*s + (j>>2)) + 4*q + (j&3)
// which makes every layer's B-fragment register-local in the lane that owns
// batch row b (lane&15), since C-layout rows are 16*mt + 4*quad + r.
#define G_W2F   0        // [t=3][s=4][lane=64][j=8] bf16  12288  (A-frags, perm)
#define G_MVF   12288    // [s=4][64][8] bf16               4096  (A-frags, perm)
#define G_D1F   16384    // [t=2][64][8] bf16               2048  (A-frags, perm)
#define G_D2F   18432    // [64][8] bf16                    1024  (A-frags, perm)
#define G_CEAB  19456    // [e=4][n=128][4] bf16 {a0,a1,a2,ce} 4096
#define G_B2P   23552    // [48] f32 (pad 0)
#define G_B3    23744    // [128] f32
#define G_BMV   24256    // [16] f32 (bm|bv)
#define G_D1C   24320    // [32] f32 (Wd1 col0 + bd1)
#define G_BD2   24448    // [16] f32 (pad 0)
#define G_W3F   24512    // [nt=8][s=2][64][8] bf16        16384  (A-frags, perm)
#define G_END   40896    // LDS: rounds to 40960 = exactly 160KiB/4 -> 4 blocks/CU

__device__ __forceinline__ unsigned short f2bf(float f) {
    unsigned int u = __float_as_uint(f);
    unsigned int r = u + 0x7fffu + ((u >> 16) & 1u);   // RNE
    return (unsigned short)(r >> 16);
}
__device__ __forceinline__ unsigned int pk(float a, float b) {
    __hip_bfloat162 h = __float22bfloat162_rn(make_float2(a, b));
    unsigned int u; __builtin_memcpy(&u, &h, 4); return u;
}

__global__ void prep_kernel(
    const float* __restrict__ W1, const float* __restrict__ b1,
    const float* __restrict__ W2, const float* __restrict__ b2,
    const float* __restrict__ W3, const float* __restrict__ b3,
    const float* __restrict__ Wm, const float* __restrict__ bm,
    const float* __restrict__ Wv, const float* __restrict__ bv,
    const float* __restrict__ Wd1, const float* __restrict__ bd1,
    const float* __restrict__ Wd2, const float* __restrict__ bd2,
    unsigned char* __restrict__ ws)
{
    const int g0 = blockIdx.x * TPB + threadIdx.x;
    const int gs = gridDim.x * TPB;
    // W2 as A-fragments of s^T = W2 . x1^T, permuted K
    unsigned short* w2f = (unsigned short*)(ws + G_W2F);
    for (int i = g0; i < 6144; i += gs) {
        int j = i & 7, lane = (i >> 3) & 63, ts = i >> 9;
        int t = ts >> 2, s = ts & 3, q = lane >> 4;
        int n = 16 * t + (lane & 15);
        int phys = 16 * (2 * s + (j >> 2)) + 4 * q + (j & 3);   // 0..127
        w2f[i] = (n < 39) ? f2bf(W2[n * 128 + phys]) : 0;
    }
    // W3 as A-fragments of x3^T = W3 . s^T, permuted K (39 padded to 64)
    unsigned short* w3f = (unsigned short*)(ws + G_W3F);
    for (int i = g0; i < 8192; i += gs) {
        int j = i & 7, lane = (i >> 3) & 63, ns = i >> 9;
        int nt = ns >> 1, s = ns & 1, q = lane >> 4;
        int n = 16 * nt + (lane & 15);
        int phys = 16 * (2 * s + (j >> 2)) + 4 * q + (j & 3);   // 0..63
        w3f[i] = (phys < 39) ? f2bf(W3[n * 39 + phys]) : 0;
    }
    // Wm|Wv as A-fragments, permuted K=128
    unsigned short* mvf = (unsigned short*)(ws + G_MVF);
    for (int i = g0; i < 2048; i += gs) {
        int j = i & 7, lane = (i >> 3) & 63, s = i >> 9;
        int q = lane >> 4, n = lane & 15;
        int phys = 16 * (2 * s + (j >> 2)) + 4 * q + (j & 3);
        mvf[i] = f2bf(n < 8 ? Wm[n * 128 + phys] : Wv[(n - 8) * 128 + phys]);
    }
    // Wd1 (cols 5..24) as A-fragments, permuted K=32 (20 padded)
    unsigned short* d1f = (unsigned short*)(ws + G_D1F);
    for (int i = g0; i < 1024; i += gs) {
        int j = i & 7, lane = (i >> 3) & 63, tt = i >> 9;
        int q = lane >> 4, n = 16 * tt + (lane & 15);
        int phys = 16 * (j >> 2) + 4 * q + (j & 3);             // 0..31
        d1f[i] = (phys < 20) ? f2bf(Wd1[n * 25 + 5 + phys]) : 0;
    }
    // Wd2 as A-fragments, permuted K=32
    unsigned short* d2f = (unsigned short*)(ws + G_D2F);
    for (int i = g0; i < 512; i += gs) {
        int j = i & 7, lane = i >> 3;
        int q = lane >> 4, n = lane & 15;
        int phys = 16 * (j >> 2) + 4 * q + (j & 3);
        d2f[i] = (n < 12) ? f2bf(Wd2[n * 32 + phys]) : 0;
    }
    unsigned short* ceab = (unsigned short*)(ws + G_CEAB);
    for (int i = g0; i < 2048; i += gs) {           // [e][n][4] {a0,a1,a2,ce}
        int c = i & 3, n = (i >> 2) & 127, e = i >> 9;
        float v = (c < 3) ? W1[n * 13 + 10 + c]
                          : (W1[n * 13 + 0] + W1[n * 13 + 6 + e] + b1[n]);
        ceab[i] = f2bf(v);
    }
    float* fb = (float*)(ws + G_B2P);
    for (int i = g0; i < 48; i += gs) fb[i] = (i < 39) ? b2[i] : 0.f;
    fb = (float*)(ws + G_B3);
    for (int i = g0; i < 128; i += gs) fb[i] = b3[i];
    fb = (float*)(ws + G_BMV);
    for (int i = g0; i < 16; i += gs) fb[i] = (i < 8) ? bm[i] : bv[i - 8];
    fb = (float*)(ws + G_D1C);
    for (int i = g0; i < 32; i += gs) fb[i] = Wd1[i * 25 + 0] + bd1[i];
    fb = (float*)(ws + G_BD2);
    for (int i = g0; i < 16; i += gs) fb[i] = (i < 12) ? bd2[i] : 0.f;
}

union S8 { short8 v; uint4 u; };

#define MFMA(a, b, c) __builtin_amdgcn_mfma_f32_16x16x32_bf16(a, b, c, 0, 0, 0)

// Zero-relayout K-permuted body (r4) + FULL weight image staged in LDS.
// Rationale: occupancy 17.5->40% across r0..r6 never moved dur from ~72us ->
// bottleneck is the ~95 scattered per-lane L1/L2 weight loads per wave
// (200-900cy each), not TLP. LDS fragment reads are ~120cy latency, 12cy
// throughput, conflict-free (consecutive lanes -> consecutive 16B).
// 40896B LDS rounds to 40960 = exactly 4 blocks/CU.
__global__ __launch_bounds__(TPB, 2) void vae_mfma(
    const float* __restrict__ ic, const float* __restrict__ cc,
    const float* __restrict__ eps,
    const unsigned char* __restrict__ ws,
    float* __restrict__ out, int B)
{
    __shared__ __attribute__((aligned(16))) unsigned char lds[G_END];
    const int tid = threadIdx.x;

    {   // weight image -> LDS (linear, coalesced; L2-hot)
        const uint4* src = (const uint4*)ws;
        uint4* dst = (uint4*)lds;
        #pragma unroll
        for (int it = 0; it < 10; it++) {
            int idx = it * TPB + tid;
            if (idx < G_END / 16) dst[idx] = src[idx];
        }
    }
    __syncthreads();

    const int lane = tid & 63, w = tid >> 6;
    const int quad = lane >> 4, n16 = lane & 15;
    const bool q0 = (quad == 0);
    const long rb = ((long)blockIdx.x * 4 + w) * 16;
    const long Rl = rb + n16;              // this lane's batch row

    // ---- q0 lanes: predicate packs per edge (pre-packed bf16 pairs, 8 u32) ----
    unsigned int bpx[4] = {0,0,0,0}, bpy[4] = {0,0,0,0};
    if (q0) {
        const float* crow = cc + Rl * 30;
        float2 u0 = *(const float2*)(crow);
        float2 u1 = *(const float2*)(crow + 2);
        float2 u2 = *(const float2*)(crow + 10);
        float2 u3 = *(const float2*)(crow + 12);
        bpx[0] = pk(u0.x, u2.x); bpy[0] = pk(crow[14], 1.0f);
        bpx[1] = pk(u0.y, u2.y); bpy[1] = pk(crow[18], 1.0f);
        bpx[2] = pk(u1.x, u3.x); bpy[2] = pk(crow[22], 1.0f);
        bpx[3] = pk(u1.y, u3.y); bpy[3] = pk(crow[26], 1.0f);
    }

    // ---- W2 A-frags resident (from LDS) + per-quad bias vectors ----
    S8 W2F[12];
    #pragma unroll
    for (int ts = 0; ts < 12; ts++)
        W2F[ts].u = *(const uint4*)(lds + G_W2F + (ts * 64 + lane) * 16);
    const float* b2p = (const float*)(lds + G_B2P);
    f32x4 b2q[3];
    #pragma unroll
    for (int t = 0; t < 3; t++)
        b2q[t] = *(const f32x4*)(b2p + 16 * t + 4 * quad);

    f32x4 ss0 = {0,0,0,0}, ss1 = {0,0,0,0}, ss2 = {0,0,0,0};

    // ---- message MLP: L1 (x1^T tiles) -> in-reg pack -> L2 (s^T), per edge ----
    #pragma unroll
    for (int e = 0; e < 4; e++) {
        S8 bp;                                   // B = p-vector (k=0..3 in q0)
        bp.u.x = bpx[e]; bp.u.y = bpy[e]; bp.u.z = 0u; bp.u.w = 0u;
        const unsigned long long* cb =
            (const unsigned long long*)(lds + G_CEAB + e * 1024);
        S8 xf[4];                                // x1^T B-frags for L2 (perm K)
        #pragma unroll
        for (int mt = 0; mt < 8; mt++) {
            unsigned long long bw = cb[mt * 16 + n16];
            S8 af;                               // A = ceab rows (k=0..3 in q0)
            af.u.x = q0 ? (unsigned int)bw : 0u;
            af.u.y = q0 ? (unsigned int)(bw >> 32) : 0u;
            af.u.z = 0u; af.u.w = 0u;
            f32x4 z4 = {0,0,0,0};
            f32x4 cr = MFMA(af.v, bp.v, z4);     // lane: x1[b=n16][16mt+4q+r]
            unsigned int lo = pk(fmaxf(cr[0], 0.f), fmaxf(cr[1], 0.f));
            unsigned int hi = pk(fmaxf(cr[2], 0.f), fmaxf(cr[3], 0.f));
            if ((mt & 1) == 0) { xf[mt >> 1].u.x = lo; xf[mt >> 1].u.y = hi; }
            else               { xf[mt >> 1].u.z = lo; xf[mt >> 1].u.w = hi; }
        }
        f32x4 c0 = b2q[0], c1 = b2q[1], c2 = b2q[2];
        #pragma unroll
        for (int s = 0; s < 4; s++) {
            c0 = MFMA(W2F[s].v,     xf[s].v, c0);
            c1 = MFMA(W2F[4 + s].v, xf[s].v, c1);
            c2 = MFMA(W2F[8 + s].v, xf[s].v, c2);
        }
        #pragma unroll
        for (int r = 0; r < 4; r++) {
            ss0[r] += fmaxf(c0[r], 0.f);
            ss1[r] += fmaxf(c1[r], 0.f);
            ss2[r] += fmaxf(c2[r], 0.f);
        }
    }

    // ---- s^T B-frags (K=64, tiles 3 valid + 1 zero pad) ----
    S8 sf0, sf1;
    sf0.u.x = pk(ss0[0], ss0[1]); sf0.u.y = pk(ss0[2], ss0[3]);
    sf0.u.z = pk(ss1[0], ss1[1]); sf0.u.w = pk(ss1[2], ss1[3]);
    sf1.u.x = pk(ss2[0], ss2[1]); sf1.u.y = pk(ss2[2], ss2[3]);
    sf1.u.z = 0u; sf1.u.w = 0u;   // rows 48..63 pad (rows 39..47 exact zero)

    // ---- L3: x3^T = W3 . s^T ; pack heads B-frags on the fly ----
    const uint4* w3l = (const uint4*)(lds + G_W3F);
    const float* b3p = (const float*)(lds + G_B3);
    S8 hf[4];
    #pragma unroll
    for (int nt = 0; nt < 8; nt++) {
        f32x4 c = *(const f32x4*)(b3p + nt * 16 + 4 * quad);
        S8 a0, a1;
        a0.u = w3l[(nt * 2 + 0) * 64 + lane];
        a1.u = w3l[(nt * 2 + 1) * 64 + lane];
        c = MFMA(a0.v, sf0.v, c);
        c = MFMA(a1.v, sf1.v, c);
        unsigned int lo = pk(fmaxf(c[0], 0.f), fmaxf(c[1], 0.f));
        unsigned int hi = pk(fmaxf(c[2], 0.f), fmaxf(c[3], 0.f));
        if ((nt & 1) == 0) { hf[nt >> 1].u.x = lo; hf[nt >> 1].u.y = hi; }
        else               { hf[nt >> 1].u.z = lo; hf[nt >> 1].u.w = hi; }
    }

    // ---- heads: [mn|lv]^T, lane holds rows 4q+r of (mn0..7,lv0..7) ----
    f32x4 cm = *(const f32x4*)((const float*)(lds + G_BMV) + 4 * quad);
    #pragma unroll
    for (int s = 0; s < 4; s++) {
        S8 a; a.u = *(const uint4*)(lds + G_MVF + (s * 64 + lane) * 16);
        cm = MFMA(a.v, hf[s].v, cm);
    }

    // ---- reparameterization: lv lives in q2/q3, pull to q0/q1 ----
    const int addrLv = ((lane + 32) & 63) << 2;
    float lvv[4];
    #pragma unroll
    for (int r = 0; r < 4; r++)
        lvv[r] = __int_as_float(
            __builtin_amdgcn_ds_bpermute(addrLv, __float_as_int(cm[r])));
    float4 ev = *(const float4*)(eps + Rl * 8 + 4 * (quad & 1));
    f32x4 zz;
    zz[0] = fmaf(ev.x, __expf(0.5f * lvv[0]), cm[0]);
    zz[1] = fmaf(ev.y, __expf(0.5f * lvv[1]), cm[1]);
    zz[2] = fmaf(ev.z, __expf(0.5f * lvv[2]), cm[2]);
    zz[3] = fmaf(ev.w, __expf(0.5f * lvv[3]), cm[3]);
    // stores: q0/q1 -> means, q2/q3 -> logvar; q0/q1 -> z
    float* pml = (float*)((quad < 2) ? (out + (long)B * 12) : (out + (long)B * 20));
    *(float4*)(pml + Rl * 8 + 4 * (quad & 1)) = *(float4*)&cm;
    if (quad < 2)
        *(float4*)(out + (long)B * 28 + Rl * 8 + 4 * quad) = *(float4*)&zz;

    // ---- z exchange for decoder: q0 needs z[4..7] (from q1), q3 needs z[0..3] (from q0)
    const int addrZ = (n16 + (q0 ? 16 : 0)) << 2;
    float zr[4];
    #pragma unroll
    for (int r = 0; r < 4; r++)
        zr[r] = __int_as_float(
            __builtin_amdgcn_ds_bpermute(addrZ, __float_as_int(zz[r])));

    // ---- decoder input B-frag: phys = [icO(12) | z(8) | 0-pad] permuted ----
    const float* irow = ic + Rl * 30;
    float d0, d1, d2, d3;
    if (quad == 3)      { d0 = zr[0];    d1 = zr[1];    d2 = zr[2];    d3 = zr[3]; }
    else if (quad == 2) { d0 = irow[14]; d1 = irow[18]; d2 = irow[22]; d3 = irow[26]; }
    else {
        const float* p = irow + (quad ? 10 : 0);
        float2 u0 = *(const float2*)(p);
        float2 u1 = *(const float2*)(p + 2);
        d0 = u0.x; d1 = u0.y; d2 = u1.x; d3 = u1.y;
    }
    S8 df;
    df.u.x = pk(d0, d1);
    df.u.y = pk(d2, d3);
    df.u.z = q0 ? pk(zr[0], zr[1]) : 0u;
    df.u.w = q0 ? pk(zr[2], zr[3]) : 0u;

    // ---- decoder layer 1: h^T (2 tiles) ----
    const float* d1c = (const float*)(lds + G_D1C);
    S8 a;
    f32x4 ct = *(const f32x4*)(d1c + 4 * quad);
    a.u = *(const uint4*)(lds + G_D1F + (0 * 64 + lane) * 16);
    f32x4 h0 = MFMA(a.v, df.v, ct);
    ct = *(const f32x4*)(d1c + 16 + 4 * quad);
    a.u = *(const uint4*)(lds + G_D1F + (1 * 64 + lane) * 16);
    f32x4 h1 = MFMA(a.v, df.v, ct);
    S8 hf2;
    hf2.u.x = pk(fmaxf(h0[0], 0.f), fmaxf(h0[1], 0.f));
    hf2.u.y = pk(fmaxf(h0[2], 0.f), fmaxf(h0[3], 0.f));
    hf2.u.z = pk(fmaxf(h1[0], 0.f), fmaxf(h1[1], 0.f));
    hf2.u.w = pk(fmaxf(h1[2], 0.f), fmaxf(h1[3], 0.f));

    // ---- decoder layer 2 + sigmoid + coalesced float4 recon store ----
    f32x4 c2 = *(const f32x4*)((const float*)(lds + G_BD2) + 4 * quad);
    S8 a2; a2.u = *(const uint4*)(lds + G_D2F + lane * 16);
    c2 = MFMA(a2.v, hf2.v, c2);
    if (quad < 3) {
        float4 o;
        o.x = 1.f / (1.f + __expf(-c2[0]));
        o.y = 1.f / (1.f + __expf(-c2[1]));
        o.z = 1.f / (1.f + __expf(-c2[2]));
        o.w = 1.f / (1.f + __expf(-c2[3]));
        *(float4*)(out + Rl * 12 + 4 * quad) = o;
    }
}

extern "C" void kernel_launch(void* const* d_in, const int* in_sizes, int n_in,
                              void* d_out, int out_size, void* d_ws, size_t ws_size,
                              hipStream_t stream) {
    const float* ic  = (const float*)d_in[0];   // initial_c [B,30]
    const float* cc  = (const float*)d_in[2];   // current_c [B,30]
    const float* eps = (const float*)d_in[3];   // eps [B,8]

    const int B = in_sizes[3] / 8;              // 262144
    const int nblocks = B / 64;                 // 4096

    prep_kernel<<<PREP_BLOCKS, TPB, 0, stream>>>(
        (const float*)d_in[4],  (const float*)d_in[5],
        (const float*)d_in[6],  (const float*)d_in[7],
        (const float*)d_in[8],  (const float*)d_in[9],
        (const float*)d_in[10], (const float*)d_in[11],
        (const float*)d_in[12], (const float*)d_in[13],
        (const float*)d_in[14], (const float*)d_in[15],
        (const float*)d_in[16], (const float*)d_in[17],
        (unsigned char*)d_ws);
    vae_mfma<<<nblocks, TPB, 0, stream>>>(
        ic, cc, eps, (const unsigned char*)d_ws, (float*)d_out, B);
}